// Round 5
// baseline (70.095 us; speedup 1.0000x reference)
//
#include <hip/hip_runtime.h>

#define NCH 256
#define ROIS_ELEMS 50176000              // 800*7*7*1280

typedef float vf2 __attribute__((ext_vector_type(2)));

// One wave per (box n, level l, channel-half): all 7x7 cells, vf2 lanes (128 ch).
// 800 boxes * 5 levels * 2 halves = 8000 waves; 4 waves/block -> 2000 blocks.
// Register banks A (top fm row) / B (bottom fm row), 14 columns each, reused
// across output rows when the fm row repeats (wave-uniform branch ladder).
__global__ __launch_bounds__(256) void roi_box_kernel(
    const float* __restrict__ boxes,   // [800,4] image-space (y1,x1,y2,x2)
    const float* __restrict__ fm0,
    const float* __restrict__ fm1,
    const float* __restrict__ fm2,
    const float* __restrict__ fm3,
    const float* __restrict__ fm4,
    float* __restrict__ out,           // [800,7,7,1280]
    float* __restrict__ out_ids)       // [800] written as float
{
    const int wave = threadIdx.x >> 6;
    const int lane = threadIdx.x & 63;

    // XCD-chunked bijective swizzle: 2000 = 8 * 250 (image i -> XCD i).
    const int bswz = (blockIdx.x & 7) * 250 + (blockIdx.x >> 3);
    const int wg   = bswz * 4 + wave;          // [0, 8000)

    const int n    = wg / 10;                  // box index [0,800)
    const int rem  = wg - n * 10;
    const int l    = rem >> 1;                 // level [0,5)
    const int half = rem & 1;                  // channel half

    const float* fm;
    switch (l) {
        case 0: fm = fm0; break;
        case 1: fm = fm1; break;
        case 2: fm = fm2; break;
        case 3: fm = fm3; break;
        default: fm = fm4; break;
    }
    const int H = 128 >> l;                    // square feature map
    const float Hm1 = (float)(H - 1);
    const float scale = (float)((8 << l) * (H - 1));   // exact in f32

    const int img   = n / 100;
    const int chOff = half * 128;

    const float y1 = boxes[n * 4 + 0];
    const float x1 = boxes[n * 4 + 1];
    const float y2 = boxes[n * 4 + 2];
    const float x2 = boxes[n * 4 + 3];

    // Replicate reference numerics (explicit rounding, no fp-contract).
    const float y1n = __fdiv_rn(y1, scale);
    const float y2n = __fdiv_rn(y2, scale);
    const float x1n = __fdiv_rn(x1, scale);
    const float x2n = __fdiv_rn(x2, scale);

    // ---- x setup: per-px weights + wave-uniform column element-offsets ----
    float wx_[7];
    bool  vx_[7];
    int c0[7], c1[7];                          // x0*NCH+chOff, x1i*NCH+chOff (SGPR)
    #pragma unroll
    for (int px = 0; px < 7; ++px) {
        const float fx = __fdiv_rn((float)px, 6.0f);
        const float xs = __fmul_rn(__fadd_rn(x1n, __fmul_rn(__fsub_rn(x2n, x1n), fx)), Hm1);
        vx_[px] = (xs >= 0.0f) && (xs <= Hm1);
        const float x0f = floorf(xs);
        wx_[px] = xs - x0f;
        const int x0  = (int)fminf(fmaxf(x0f,        0.0f), Hm1);
        const int x1i = (int)fminf(fmaxf(x0f + 1.0f, 0.0f), Hm1);
        c0[px] = __builtin_amdgcn_readfirstlane(x0  * NCH + chOff);
        c1[px] = __builtin_amdgcn_readfirstlane(x1i * NCH + chOff);
    }

    vf2 A0[7], A1[7], B0[7], B1[7];            // top/bottom row banks (static idx)
    int curA = -1, curB = -1;

    #pragma unroll
    for (int py = 0; py < 7; ++py) {
        const float fy = __fdiv_rn((float)py, 6.0f);
        const float ys = __fmul_rn(__fadd_rn(y1n, __fmul_rn(__fsub_rn(y2n, y1n), fy)), Hm1);
        const bool  vy = (ys >= 0.0f) && (ys <= Hm1);
        const float y0f = floorf(ys);
        const float wy  = ys - y0f;
        const float owy = 1.0f - wy;
        const int y0  = __builtin_amdgcn_readfirstlane(
                            (int)fminf(fmaxf(y0f,        0.0f), Hm1));
        const int y1i = __builtin_amdgcn_readfirstlane(
                            (int)fminf(fmaxf(y0f + 1.0f, 0.0f), Hm1));

        const int oA = __builtin_amdgcn_readfirstlane((img * H + y0 ) * H * NCH);
        const int oB = __builtin_amdgcn_readfirstlane((img * H + y1i) * H * NCH);

        // Wave-uniform reuse ladder.
        if (y0 == curA) {
            // top row unchanged; bottom may change (clamp transitions)
            if (y1i != curB) {
                #pragma unroll
                for (int px = 0; px < 7; ++px) {
                    B0[px] = ((const vf2*)(fm + oB + c0[px]))[lane];
                    B1[px] = ((const vf2*)(fm + oB + c1[px]))[lane];
                }
            }
        } else if (y0 == curB) {
            // shift down by one row: old bottom becomes new top
            #pragma unroll
            for (int px = 0; px < 7; ++px) { A0[px] = B0[px]; A1[px] = B1[px]; }
            if (y1i != curB) {
                #pragma unroll
                for (int px = 0; px < 7; ++px) {
                    B0[px] = ((const vf2*)(fm + oB + c0[px]))[lane];
                    B1[px] = ((const vf2*)(fm + oB + c1[px]))[lane];
                }
            }
        } else {
            // jump: load both rows
            #pragma unroll
            for (int px = 0; px < 7; ++px) {
                A0[px] = ((const vf2*)(fm + oA + c0[px]))[lane];
                A1[px] = ((const vf2*)(fm + oA + c1[px]))[lane];
            }
            #pragma unroll
            for (int px = 0; px < 7; ++px) {
                B0[px] = ((const vf2*)(fm + oB + c0[px]))[lane];
                B1[px] = ((const vf2*)(fm + oB + c1[px]))[lane];
            }
        }
        curA = y0; curB = y1i;

        // Blend + non-temporal store (output is write-once).
        float* obase = out + ((n * 7 + py) * 7) * 1280 + l * NCH + chOff;
        #pragma unroll
        for (int px = 0; px < 7; ++px) {
            const float wx  = wx_[px];
            const float owx = 1.0f - wx;
            vf2 r = (A0[px] * owx + A1[px] * wx) * owy
                  + (B0[px] * owx + B1[px] * wx) * wy;
            if (!(vy && vx_[px])) { r = (vf2)0.0f; }
            __builtin_nontemporal_store(r, ((vf2*)(obase + px * 1280)) + lane);
        }
    }

    if (l == 0 && half == 0 && lane == 0) {
        out_ids[n] = (float)img;
    }
}

extern "C" void kernel_launch(void* const* d_in, const int* in_sizes, int n_in,
                              void* d_out, int out_size, void* d_ws, size_t ws_size,
                              hipStream_t stream) {
    const float* boxes = (const float*)d_in[0];
    const float* fm0   = (const float*)d_in[1];
    const float* fm1   = (const float*)d_in[2];
    const float* fm2   = (const float*)d_in[3];
    const float* fm3   = (const float*)d_in[4];
    const float* fm4   = (const float*)d_in[5];

    float* out     = (float*)d_out;
    float* out_ids = out + ROIS_ELEMS;

    roi_box_kernel<<<2000, 256, 0, stream>>>(boxes, fm0, fm1, fm2, fm3, fm4, out, out_ids);
}